// Round 15
// baseline (378.562 us; speedup 1.0000x reference)
//
#include <hip/hip_runtime.h>
#include <stdint.h>

typedef short short8 __attribute__((ext_vector_type(8)));
typedef float f32x16 __attribute__((ext_vector_type(16)));
typedef unsigned ux4 __attribute__((ext_vector_type(4)));

__device__ __forceinline__ unsigned cvtpk(float lo, float hi){
  unsigned r;
  asm("v_cvt_pk_bf16_f32 %0, %1, %2" : "=v"(r) : "v"(lo), "v"(hi));
  return r;
}

__device__ __forceinline__ short8 frag_from(unsigned a, unsigned b, unsigned c, unsigned d){
  union { unsigned u[4]; short8 s; } t;
  t.u[0] = a; t.u[1] = b; t.u[2] = c; t.u[3] = d;
  return t.s;
}

// ------- setup: W-frag pack + x->bf16 cast + target histogram + source histogram -------
__global__ void k_setup(const float* __restrict__ x, uint2* __restrict__ xb, int n4,
                        const int* __restrict__ ei, int* __restrict__ rowptr,
                        int* __restrict__ srcptr, int E,
                        const float* __restrict__ W1, const float* __restrict__ W2,
                        ux4* __restrict__ Wf)
{
  const long long tid = (long long)blockIdx.x * 256 + threadIdx.x;
  if (tid < 48 * 64) {
    const int f = (int)(tid >> 6), l = (int)(tid & 63);
    const int r = l & 31, hh = l >> 5;
    float v[8];
    if (f < 16) {
      const int mf = f >> 2, ks = f & 3;
      const int c = 32 * mf + r, kb = ks * 16 + hh * 8;
#pragma unroll
      for (int j = 0; j < 8; ++j) v[j] = W1[(kb + j) * 128 + c];
    } else {
      const int f2 = f - 16, mf2 = f2 >> 3, ks = f2 & 7;
      const int o = 32 * mf2 + r, cb = ks * 16 + hh * 8;
#pragma unroll
      for (int j = 0; j < 8; ++j) v[j] = W2[(cb + j) * 128 + o];
    }
    ux4 d;
    d.x = cvtpk(v[0], v[1]); d.y = cvtpk(v[2], v[3]);
    d.z = cvtpk(v[4], v[5]); d.w = cvtpk(v[6], v[7]);
    Wf[(long long)f * 64 + l] = d;
  }
  const long long tot = (n4 > E) ? n4 : E;
  for (long long i = tid; i < tot; i += (long long)gridDim.x * 256) {
    if (i < n4) {
      float4 v = ((const float4*)x)[i];
      uint2 o; o.x = cvtpk(v.x, v.y); o.y = cvtpk(v.z, v.w);
      xb[i] = o;
    }
    if (i < E) {
      atomicAdd(&rowptr[ei[E + i]], 1);
      atomicAdd(&srcptr[ei[i]], 1);
    }
  }
}

// ------- dual exclusive scan (rowptr, then srcptr) in one block -------
__global__ __launch_bounds__(1024)
void k_scan2(int* __restrict__ p1, int* __restrict__ p2, int N){
  __shared__ int ls[1024];
  const int t = threadIdx.x;
  const int chunk = (N + 1023) >> 10;
  const int c0 = t * chunk, c1 = min(N, c0 + chunk);
#pragma unroll 1
  for (int a = 0; a < 2; ++a) {
    int* p = a ? p2 : p1;
    int s = 0;
    for (int i = c0; i < c1; ++i) s += p[i];
    ls[t] = s;
    __syncthreads();
    for (int off = 1; off < 1024; off <<= 1) {
      int add = (t >= off) ? ls[t - off] : 0;
      __syncthreads();
      ls[t] += add;
      __syncthreads();
    }
    int run = (t == 0) ? 0 : ls[t - 1];
    for (int i = c0; i < c1; ++i) { int v = p[i]; p[i] = run; run += v; }
    __syncthreads();
  }
}

// ------- fill both permutations: eidx (target-CSR), pose (edge->target pos), esrc -------
__global__ void k_fill(const int* __restrict__ ei, int* __restrict__ rowptr,
                       int* __restrict__ srcptr, int* __restrict__ eidx,
                       int* __restrict__ pose, int* __restrict__ esrc, int E){
  for (long long i = (long long)blockIdx.x * 256 + threadIdx.x; i < E;
       i += (long long)gridDim.x * 256) {
    int tg = ei[E + i];
    int pos = atomicAdd(&rowptr[tg], 1);
    pose[i] = pos;
    eidx[pos] = (int)i;
    int sc = ei[i];
    int sp = atomicAdd(&srcptr[sc], 1);
    esrc[sp] = (int)i;
  }
}

// ------- K1: persistent, pipelined, SRC-SORTED processing (x-gather made local) -------
#define K1B 512
__global__ __launch_bounds__(K1B)
void k1_fused(const unsigned* __restrict__ xb, const int* __restrict__ ei,
              const float* __restrict__ ea, const ux4* __restrict__ Wf,
              const float* __restrict__ b1, const float* __restrict__ b2,
              const float* __restrict__ attn, const int* __restrict__ esrc,
              const int* __restrict__ pose,
              unsigned* __restrict__ msgp, float* __restrict__ scoreS, int E)
{
  __shared__ ux4 sWf[48 * 64];
  for (int i = threadIdx.x; i < 48 * 64; i += K1B) sWf[i] = Wf[i];
  __syncthreads();

  const int lane = threadIdx.x & 63;
  const int wv   = threadIdx.x >> 6;
  const int h    = lane >> 5;
  const int r31  = lane & 31;
  const long long gstep = (long long)gridDim.x * (K1B / 64) * 32;
  long long p = ((long long)blockIdx.x * (K1B / 64) + wv) * 32 + r31;
  if (p - r31 >= E) return;

  int eC = esrc[(p < E) ? p : (long long)(E - 1)];
  int srcC = ei[eC];
  int posC = pose[eC];
  unsigned ebC[4][4]; float rinC;
  {
    const float* er = ea + (long long)eC * 64 + h * 8;
    float4 v[8];
#pragma unroll
    for (int ks = 0; ks < 4; ++ks) {
      v[2*ks]   = *(const float4*)(er + ks * 16);
      v[2*ks+1] = *(const float4*)(er + ks * 16 + 4);
    }
    float ss = 0.f;
#pragma unroll
    for (int k8 = 0; k8 < 8; ++k8) {
      ss = fmaf(v[k8].x, v[k8].x, ss); ss = fmaf(v[k8].y, v[k8].y, ss);
      ss = fmaf(v[k8].z, v[k8].z, ss); ss = fmaf(v[k8].w, v[k8].w, ss);
    }
    ss += __shfl_xor(ss, 32);
    rinC = 1.0f / (sqrtf(ss) + 1e-8f);
#pragma unroll
    for (int ks = 0; ks < 4; ++ks) {
      ebC[ks][0] = cvtpk(v[2*ks].x,   v[2*ks].y);
      ebC[ks][1] = cvtpk(v[2*ks].z,   v[2*ks].w);
      ebC[ks][2] = cvtpk(v[2*ks+1].x, v[2*ks+1].y);
      ebC[ks][3] = cvtpk(v[2*ks+1].z, v[2*ks+1].w);
    }
  }
  long long pn = p + gstep;
  bool hasN = (pn - r31) < E;
  int eN = 0;
  if (hasN) eN = esrc[(pn < E) ? pn : (long long)(E - 1)];

  while (true) {
    float4 eaN[8]; int srcN = 0, posN = 0;
    if (hasN) {
      srcN = ei[eN];
      posN = pose[eN];
      const float* er = ea + (long long)eN * 64 + h * 8;
#pragma unroll
      for (int ks = 0; ks < 4; ++ks) {
        eaN[2*ks]   = *(const float4*)(er + ks * 16);
        eaN[2*ks+1] = *(const float4*)(er + ks * 16 + 4);
      }
    }
    long long pnn = pn + gstep;
    bool hasNN = hasN && ((pnn - r31) < E);
    int eNN = 0;
    if (hasNN) eNN = esrc[(pnn < E) ? pnn : (long long)(E - 1)];

    const unsigned* xrow = xb + (long long)srcC * 64;
    uint2 xw[4];
#pragma unroll
    for (int rq = 0; rq < 4; ++rq)
      xw[rq] = *(const uint2*)(xrow + (8*rq + 4*h) / 2);
    asm volatile("" ::: "memory");

    unsigned hb[8][4];
#pragma unroll
    for (int mf = 0; mf < 4; ++mf) {
      f32x16 a1;
#pragma unroll
      for (int i = 0; i < 16; ++i) a1[i] = 0.f;
#pragma unroll
      for (int ks = 0; ks < 4; ++ks) {
        ux4 w = sWf[(mf * 4 + ks) * 64 + lane];
        a1 = __builtin_amdgcn_mfma_f32_32x32x16_bf16(
            frag_from(w.x, w.y, w.z, w.w),
            frag_from(ebC[ks][0], ebC[ks][1], ebC[ks][2], ebC[ks][3]), a1, 0, 0, 0);
      }
      float hv[16];
#pragma unroll
      for (int rq = 0; rq < 4; ++rq) {
        float4 bc = *(const float4*)(b1 + 32*mf + 8*rq + 4*h);
#pragma unroll
        for (int i = 0; i < 4; ++i) {
          float pre = fmaf(a1[rq*4+i], rinC, ((const float*)&bc)[i]);
          float e2  = __expf(2.0f * pre);
          hv[rq*4+i] = 1.0f - 2.0f / (e2 + 1.0f);
        }
      }
#pragma unroll
      for (int q = 0; q < 2; ++q) {
        unsigned A = cvtpk(hv[q*8+0], hv[q*8+1]);
        unsigned B = cvtpk(hv[q*8+2], hv[q*8+3]);
        unsigned C = cvtpk(hv[q*8+4], hv[q*8+5]);
        unsigned D = cvtpk(hv[q*8+6], hv[q*8+7]);
        unsigned Axr = (unsigned)__shfl_xor((int)A, 32);
        unsigned Bxr = (unsigned)__shfl_xor((int)B, 32);
        unsigned Cxr = (unsigned)__shfl_xor((int)C, 32);
        unsigned Dxr = (unsigned)__shfl_xor((int)D, 32);
        hb[2*mf+q][0] = h ? Cxr : A;
        hb[2*mf+q][1] = h ? Dxr : B;
        hb[2*mf+q][2] = h ? C   : Axr;
        hb[2*mf+q][3] = h ? D   : Bxr;
      }
    }

    float score = 0.f;
#pragma unroll
    for (int mf2 = 0; mf2 < 4; ++mf2) {
      uint2 xwN[4];
      if (mf2 < 3) {
#pragma unroll
        for (int rq = 0; rq < 4; ++rq)
          xwN[rq] = *(const uint2*)(xrow + (32*(mf2+1) + 8*rq + 4*h) / 2);
      }
      f32x16 a2;
#pragma unroll
      for (int i = 0; i < 16; ++i) a2[i] = 0.f;
#pragma unroll
      for (int ks = 0; ks < 8; ++ks) {
        ux4 w = sWf[(16 + mf2 * 8 + ks) * 64 + lane];
        a2 = __builtin_amdgcn_mfma_f32_32x32x16_bf16(
            frag_from(w.x, w.y, w.z, w.w),
            frag_from(hb[ks][0], hb[ks][1], hb[ks][2], hb[ks][3]), a2, 0, 0, 0);
      }
      unsigned pk[8];
#pragma unroll
      for (int rq = 0; rq < 4; ++rq) {
        const int o0 = 32*mf2 + 8*rq + 4*h;
        float4 b2c = *(const float4*)(b2 + o0);
        float4 atc = *(const float4*)(attn + o0);
        float x0 = __uint_as_float(xw[rq].x << 16);
        float x1 = __uint_as_float(xw[rq].x & 0xffff0000u);
        float x2 = __uint_as_float(xw[rq].y << 16);
        float x3 = __uint_as_float(xw[rq].y & 0xffff0000u);
        float m0 = (a2[rq*4+0] + b2c.x) * x0;
        float m1 = (a2[rq*4+1] + b2c.y) * x1;
        float m2 = (a2[rq*4+2] + b2c.z) * x2;
        float m3 = (a2[rq*4+3] + b2c.w) * x3;
        score = fmaf(m0, atc.x, score);
        score = fmaf(m1, atc.y, score);
        score = fmaf(m2, atc.z, score);
        score = fmaf(m3, atc.w, score);
        pk[2*rq]   = cvtpk(m0, m1);
        pk[2*rq+1] = cvtpk(m2, m3);
      }
      if (p < E) {
        ux4* dst = (ux4*)(msgp + (long long)posC * 64 + 16*mf2 + 8*h);
        ux4 s0, s1;
        s0.x = pk[0]; s0.y = pk[1]; s0.z = pk[2]; s0.w = pk[3];
        s1.x = pk[4]; s1.y = pk[5]; s1.z = pk[6]; s1.w = pk[7];
        dst[0] = s0; dst[1] = s1;
      }
      if (mf2 < 3) {
#pragma unroll
        for (int rq = 0; rq < 4; ++rq) xw[rq] = xwN[rq];
      }
    }
    score += __shfl_xor(score, 32);
    if (h == 0 && p < E) scoreS[posC] = score;

    if (!hasN) break;
    float ss = 0.f;
#pragma unroll
    for (int k8 = 0; k8 < 8; ++k8) {
      ss = fmaf(eaN[k8].x, eaN[k8].x, ss); ss = fmaf(eaN[k8].y, eaN[k8].y, ss);
      ss = fmaf(eaN[k8].z, eaN[k8].z, ss); ss = fmaf(eaN[k8].w, eaN[k8].w, ss);
    }
    ss += __shfl_xor(ss, 32);
    rinC = 1.0f / (sqrtf(ss) + 1e-8f);
#pragma unroll
    for (int ks = 0; ks < 4; ++ks) {
      ebC[ks][0] = cvtpk(eaN[2*ks].x,   eaN[2*ks].y);
      ebC[ks][1] = cvtpk(eaN[2*ks].z,   eaN[2*ks].w);
      ebC[ks][2] = cvtpk(eaN[2*ks+1].x, eaN[2*ks+1].y);
      ebC[ks][3] = cvtpk(eaN[2*ks+1].z, eaN[2*ks+1].w);
    }
    srcC = srcN; posC = posN; p = pn; pn = pnn; hasN = hasNN; eN = eNN;
  }
}

// ------- gather: softmax + weighted sum; writes weights via eidx (R13-proven) -------
__global__ __launch_bounds__(256)
void k_gather(const unsigned* __restrict__ msgp, const float* __restrict__ scoreS,
              const int* __restrict__ rowptr, const int* __restrict__ eidx,
              float* __restrict__ wreg, float* __restrict__ out, int N)
{
  const int lane = threadIdx.x & 63;
  const int node = blockIdx.x * 4 + (threadIdx.x >> 6);
  if (node >= N) return;
  const int end   = rowptr[node];
  const int start = node ? rowptr[node - 1] : 0;
  const int L     = end - start;

  float2 acc; acc.x = 0.f; acc.y = 0.f;

  if (L <= 64) {
    float sc = (lane < L) ? scoreS[start + lane] : -3.4e38f;
    float mn = sc;
#pragma unroll
    for (int off = 32; off; off >>= 1) mn = fmaxf(mn, __shfl_xor(mn, off));
    float ex = (lane < L) ? __expf(sc - mn) : 0.f;
    float s = ex;
#pragma unroll
    for (int off = 32; off; off >>= 1) s += __shfl_xor(s, off);
    const float w = ex / (s + 1e-16f);
    if (lane < L) wreg[eidx[start + lane]] = w;
#pragma unroll 4
    for (int j2 = 0; j2 < L; ++j2) {
      float wj = __shfl(w, j2);
      unsigned md = msgp[(long long)(start + j2) * 64 + lane];
      acc.x = fmaf(wj, __uint_as_float(md << 16),          acc.x);
      acc.y = fmaf(wj, __uint_as_float(md & 0xffff0000u), acc.y);
    }
  } else {
    float m = -3.4e38f, s = 0.f;
    for (int c0 = 0; c0 < L; c0 += 64) {
      const int j = c0 + lane;
      float sc = (j < L) ? scoreS[start + j] : -3.4e38f;
      float cm = sc;
#pragma unroll
      for (int off = 32; off; off >>= 1) cm = fmaxf(cm, __shfl_xor(cm, off));
      const float mn = fmaxf(m, cm);
      float ex = (j < L) ? __expf(sc - mn) : 0.f;
#pragma unroll
      for (int off = 32; off; off >>= 1) ex += __shfl_xor(ex, off);
      s = s * __expf(m - mn) + ex;
      m = mn;
    }
    const float inv = 1.0f / (s + 1e-16f);
    for (int c0 = 0; c0 < L; c0 += 64) {
      const int j = c0 + lane;
      float w = (j < L) ? __expf(scoreS[start + j] - m) * inv : 0.f;
      if (j < L) wreg[eidx[start + j]] = w;
      const int jn = min(64, L - c0);
#pragma unroll 4
      for (int j2 = 0; j2 < jn; ++j2) {
        float wj = __shfl(w, j2);
        unsigned md = msgp[(long long)(start + c0 + j2) * 64 + lane];
        acc.x = fmaf(wj, __uint_as_float(md << 16),          acc.x);
        acc.y = fmaf(wj, __uint_as_float(md & 0xffff0000u), acc.y);
      }
    }
  }
  const int mf2 = lane >> 4, hh = (lane >> 3) & 1, rq = (lane >> 1) & 3, half = lane & 1;
  const int ch0 = 32*mf2 + 8*rq + 4*hh + 2*half;
  *(float2*)(out + (long long)node * 128 + ch0) = acc;
}

extern "C" void kernel_launch(void* const* d_in, const int* in_sizes, int n_in,
                              void* d_out, int out_size, void* d_ws, size_t ws_size,
                              hipStream_t stream)
{
  const float* x    = (const float*)d_in[0];
  const int*   ei   = (const int*)d_in[1];
  const float* ea   = (const float*)d_in[2];
  const float* W1   = (const float*)d_in[3];
  const float* b1   = (const float*)d_in[4];
  const float* W2   = (const float*)d_in[5];
  const float* b2   = (const float*)d_in[6];
  const float* attn = (const float*)d_in[7];
  const int N = in_sizes[0] / 128;
  const int E = in_sizes[2] / 64;
  if (E <= 0 || N <= 0) return;

  float* out  = (float*)d_out;
  float* wreg = out + (long long)N * 128;

  // d_out node-region scratch (dead before gather's out writes):
  ux4*      Wf   = (ux4*)d_out;                                   // 48K
  unsigned* xb   = (unsigned*)((char*)d_out + 65536);             // N*256
  size_t    offS = 65536 + (size_t)N * 256;
  int*      esrc = (int*)((char*)d_out + offS);                   // E*4
  int*      pose = (int*)((char*)d_out + offS + (size_t)E * 4);   // E*4
  const size_t doNeed = offS + (size_t)E * 8;

  char* wsb = (char*)d_ws;
  unsigned* msgp   = (unsigned*)wsb;                                  // E*256
  float*    scoreS = (float*)(wsb + (size_t)E * 256);                 // E*4
  int*      rowptr = (int*)(wsb + (size_t)E * 260);                   // N*4
  int*      srcptr = (int*)(wsb + (size_t)E * 260 + (size_t)N * 4);   // N*4
  int*      eidx   = (int*)(wsb + (size_t)E * 260 + (size_t)N * 8);   // E*4
  const size_t need = (size_t)E * 264 + (size_t)N * 8;
  if (ws_size < need) return;
  if ((size_t)out_size < (size_t)N * 128 + (size_t)E) return;
  if ((size_t)N * 512 < doNeed) return;

  (void)hipMemsetAsync(rowptr, 0, (size_t)N * 8, stream);   // rowptr + srcptr
  k_setup<<<1024, 256, 0, stream>>>(x, (uint2*)xb, N * 32, ei, rowptr, srcptr, E,
                                    W1, W2, Wf);
  k_scan2<<<1, 1024, 0, stream>>>(rowptr, srcptr, N);
  k_fill<<<1024, 256, 0, stream>>>(ei, rowptr, srcptr, eidx, pose, esrc, E);
  const long long nwaves = ((long long)E + 31) / 32;
  const int grid = (int)min((long long)512, (nwaves + (K1B/64) - 1) / (K1B/64));
  k1_fused<<<grid, K1B, 0, stream>>>(xb, ei, ea, Wf, b1, b2, attn,
                                     esrc, pose, msgp, scoreS, E);
  k_gather<<<(N + 3) / 4, 256, 0, stream>>>(msgp, scoreS, rowptr, eidx,
                                            wreg, out, N);
}

// Round 16
// 260.061 us; speedup vs baseline: 1.4557x; 1.4557x over previous
//
#include <hip/hip_runtime.h>
#include <stdint.h>

typedef short short8 __attribute__((ext_vector_type(8)));
typedef float f32x16 __attribute__((ext_vector_type(16)));
typedef unsigned ux4 __attribute__((ext_vector_type(4)));

__device__ __forceinline__ unsigned cvtpk(float lo, float hi){
  unsigned r;
  asm("v_cvt_pk_bf16_f32 %0, %1, %2" : "=v"(r) : "v"(lo), "v"(hi));
  return r;
}

__device__ __forceinline__ short8 frag_from(unsigned a, unsigned b, unsigned c, unsigned d){
  union { unsigned u[4]; short8 s; } t;
  t.u[0] = a; t.u[1] = b; t.u[2] = c; t.u[3] = d;
  return t.s;
}

// ---------------- setup: W-frag pack + x->bf16 cast + target histogram (fused) -------
__global__ void k_setup(const float* __restrict__ x, uint2* __restrict__ xb, int n4,
                        const int* __restrict__ ei, int* __restrict__ rowptr, int E,
                        const float* __restrict__ W1, const float* __restrict__ W2,
                        ux4* __restrict__ Wf)
{
  const long long tid = (long long)blockIdx.x * 256 + threadIdx.x;
  if (tid < 48 * 64) {
    const int f = (int)(tid >> 6), l = (int)(tid & 63);
    const int r = l & 31, hh = l >> 5;
    float v[8];
    if (f < 16) {
      const int mf = f >> 2, ks = f & 3;
      const int c = 32 * mf + r, kb = ks * 16 + hh * 8;
#pragma unroll
      for (int j = 0; j < 8; ++j) v[j] = W1[(kb + j) * 128 + c];
    } else {
      const int f2 = f - 16, mf2 = f2 >> 3, ks = f2 & 7;
      const int o = 32 * mf2 + r, cb = ks * 16 + hh * 8;
#pragma unroll
      for (int j = 0; j < 8; ++j) v[j] = W2[(cb + j) * 128 + o];
    }
    ux4 d;
    d.x = cvtpk(v[0], v[1]); d.y = cvtpk(v[2], v[3]);
    d.z = cvtpk(v[4], v[5]); d.w = cvtpk(v[6], v[7]);
    Wf[(long long)f * 64 + l] = d;
  }
  const long long tot = (n4 > E) ? n4 : E;
  for (long long i = tid; i < tot; i += (long long)gridDim.x * 256) {
    if (i < n4) {
      float4 v = ((const float4*)x)[i];
      uint2 o; o.x = cvtpk(v.x, v.y); o.y = cvtpk(v.z, v.w);
      xb[i] = o;
    }
    if (i < E) atomicAdd(&rowptr[ei[E + i]], 1);
  }
}

__global__ __launch_bounds__(1024)
void k_scan(int* __restrict__ p, int N){
  __shared__ int ls[1024];
  const int t = threadIdx.x;
  const int chunk = (N + 1023) >> 10;
  const int c0 = t * chunk, c1 = min(N, c0 + chunk);
  int s = 0;
  for (int i = c0; i < c1; ++i) s += p[i];
  ls[t] = s;
  __syncthreads();
  for (int off = 1; off < 1024; off <<= 1) {
    int add = (t >= off) ? ls[t - off] : 0;
    __syncthreads();
    ls[t] += add;
    __syncthreads();
  }
  int run = (t == 0) ? 0 : ls[t - 1];
  for (int i = c0; i < c1; ++i) { int v = p[i]; p[i] = run; run += v; }
}

__global__ void k_fill(const int* __restrict__ ei, int* __restrict__ rowptr,
                       int* __restrict__ pose, int* __restrict__ eidx, int E){
  for (long long i = (long long)blockIdx.x * 256 + threadIdx.x; i < E;
       i += (long long)gridDim.x * 256) {
    int tg = ei[E + i];
    int pos = atomicAdd(&rowptr[tg], 1);
    if (pose) pose[i] = pos;
    eidx[pos] = (int)i;
  }
}

// ---------------- K1: persistent, pipelined (R11/R13-exact body) ----------------
#define K1B 512
__global__ __launch_bounds__(K1B)
void k1_fused(const unsigned* __restrict__ xb, const int* __restrict__ ei,
              const float* __restrict__ ea, const ux4* __restrict__ Wf,
              const float* __restrict__ b1, const float* __restrict__ b2,
              const float* __restrict__ attn, const int* __restrict__ eidx,
              unsigned* __restrict__ msgp, float* __restrict__ scoreS, int E)
{
  __shared__ ux4 sWf[48 * 64];
  for (int i = threadIdx.x; i < 48 * 64; i += K1B) sWf[i] = Wf[i];
  __syncthreads();

  const int lane = threadIdx.x & 63;
  const int wv   = threadIdx.x >> 6;
  const int h    = lane >> 5;
  const int r31  = lane & 31;
  const long long gstep = (long long)gridDim.x * (K1B / 64) * 32;
  long long p = ((long long)blockIdx.x * (K1B / 64) + wv) * 32 + r31;
  if (p - r31 >= E) return;

  int eC = eidx[(p < E) ? p : (long long)(E - 1)];
  int srcC = ei[eC];
  unsigned ebC[4][4]; float rinC;
  {
    const float* er = ea + (long long)eC * 64 + h * 8;
    float4 v[8];
#pragma unroll
    for (int ks = 0; ks < 4; ++ks) {
      v[2*ks]   = *(const float4*)(er + ks * 16);
      v[2*ks+1] = *(const float4*)(er + ks * 16 + 4);
    }
    float ss = 0.f;
#pragma unroll
    for (int k8 = 0; k8 < 8; ++k8) {
      ss = fmaf(v[k8].x, v[k8].x, ss); ss = fmaf(v[k8].y, v[k8].y, ss);
      ss = fmaf(v[k8].z, v[k8].z, ss); ss = fmaf(v[k8].w, v[k8].w, ss);
    }
    ss += __shfl_xor(ss, 32);
    rinC = 1.0f / (sqrtf(ss) + 1e-8f);
#pragma unroll
    for (int ks = 0; ks < 4; ++ks) {
      ebC[ks][0] = cvtpk(v[2*ks].x,   v[2*ks].y);
      ebC[ks][1] = cvtpk(v[2*ks].z,   v[2*ks].w);
      ebC[ks][2] = cvtpk(v[2*ks+1].x, v[2*ks+1].y);
      ebC[ks][3] = cvtpk(v[2*ks+1].z, v[2*ks+1].w);
    }
  }
  long long pn = p + gstep;
  bool hasN = (pn - r31) < E;
  int eN = 0;
  if (hasN) eN = eidx[(pn < E) ? pn : (long long)(E - 1)];

  while (true) {
    float4 eaN[8]; int srcN = 0;
    if (hasN) {
      srcN = ei[eN];
      const float* er = ea + (long long)eN * 64 + h * 8;
#pragma unroll
      for (int ks = 0; ks < 4; ++ks) {
        eaN[2*ks]   = *(const float4*)(er + ks * 16);
        eaN[2*ks+1] = *(const float4*)(er + ks * 16 + 4);
      }
    }
    long long pnn = pn + gstep;
    bool hasNN = hasN && ((pnn - r31) < E);
    int eNN = 0;
    if (hasNN) eNN = eidx[(pnn < E) ? pnn : (long long)(E - 1)];

    const unsigned* xrow = xb + (long long)srcC * 64;
    uint2 xw[4];
#pragma unroll
    for (int rq = 0; rq < 4; ++rq)
      xw[rq] = *(const uint2*)(xrow + (8*rq + 4*h) / 2);
    asm volatile("" ::: "memory");

    unsigned hb[8][4];
#pragma unroll
    for (int mf = 0; mf < 4; ++mf) {
      f32x16 a1;
#pragma unroll
      for (int i = 0; i < 16; ++i) a1[i] = 0.f;
#pragma unroll
      for (int ks = 0; ks < 4; ++ks) {
        ux4 w = sWf[(mf * 4 + ks) * 64 + lane];
        a1 = __builtin_amdgcn_mfma_f32_32x32x16_bf16(
            frag_from(w.x, w.y, w.z, w.w),
            frag_from(ebC[ks][0], ebC[ks][1], ebC[ks][2], ebC[ks][3]), a1, 0, 0, 0);
      }
      float hv[16];
#pragma unroll
      for (int rq = 0; rq < 4; ++rq) {
        float4 bc = *(const float4*)(b1 + 32*mf + 8*rq + 4*h);
#pragma unroll
        for (int i = 0; i < 4; ++i) {
          float pre = fmaf(a1[rq*4+i], rinC, ((const float*)&bc)[i]);
          float e2  = __expf(2.0f * pre);
          hv[rq*4+i] = 1.0f - 2.0f / (e2 + 1.0f);
        }
      }
#pragma unroll
      for (int q = 0; q < 2; ++q) {
        unsigned A = cvtpk(hv[q*8+0], hv[q*8+1]);
        unsigned B = cvtpk(hv[q*8+2], hv[q*8+3]);
        unsigned C = cvtpk(hv[q*8+4], hv[q*8+5]);
        unsigned D = cvtpk(hv[q*8+6], hv[q*8+7]);
        unsigned Axr = (unsigned)__shfl_xor((int)A, 32);
        unsigned Bxr = (unsigned)__shfl_xor((int)B, 32);
        unsigned Cxr = (unsigned)__shfl_xor((int)C, 32);
        unsigned Dxr = (unsigned)__shfl_xor((int)D, 32);
        hb[2*mf+q][0] = h ? Cxr : A;
        hb[2*mf+q][1] = h ? Dxr : B;
        hb[2*mf+q][2] = h ? C   : Axr;
        hb[2*mf+q][3] = h ? D   : Bxr;
      }
    }

    float score = 0.f;
#pragma unroll
    for (int mf2 = 0; mf2 < 4; ++mf2) {
      uint2 xwN[4];
      if (mf2 < 3) {
#pragma unroll
        for (int rq = 0; rq < 4; ++rq)
          xwN[rq] = *(const uint2*)(xrow + (32*(mf2+1) + 8*rq + 4*h) / 2);
      }
      f32x16 a2;
#pragma unroll
      for (int i = 0; i < 16; ++i) a2[i] = 0.f;
#pragma unroll
      for (int ks = 0; ks < 8; ++ks) {
        ux4 w = sWf[(16 + mf2 * 8 + ks) * 64 + lane];
        a2 = __builtin_amdgcn_mfma_f32_32x32x16_bf16(
            frag_from(w.x, w.y, w.z, w.w),
            frag_from(hb[ks][0], hb[ks][1], hb[ks][2], hb[ks][3]), a2, 0, 0, 0);
      }
      unsigned pk[8];
#pragma unroll
      for (int rq = 0; rq < 4; ++rq) {
        const int o0 = 32*mf2 + 8*rq + 4*h;
        float4 b2c = *(const float4*)(b2 + o0);
        float4 atc = *(const float4*)(attn + o0);
        float x0 = __uint_as_float(xw[rq].x << 16);
        float x1 = __uint_as_float(xw[rq].x & 0xffff0000u);
        float x2 = __uint_as_float(xw[rq].y << 16);
        float x3 = __uint_as_float(xw[rq].y & 0xffff0000u);
        float m0 = (a2[rq*4+0] + b2c.x) * x0;
        float m1 = (a2[rq*4+1] + b2c.y) * x1;
        float m2 = (a2[rq*4+2] + b2c.z) * x2;
        float m3 = (a2[rq*4+3] + b2c.w) * x3;
        score = fmaf(m0, atc.x, score);
        score = fmaf(m1, atc.y, score);
        score = fmaf(m2, atc.z, score);
        score = fmaf(m3, atc.w, score);
        pk[2*rq]   = cvtpk(m0, m1);
        pk[2*rq+1] = cvtpk(m2, m3);
      }
      if (p < E) {
        ux4* dst = (ux4*)(msgp + p * 64 + 16*mf2 + 8*h);
        ux4 s0, s1;
        s0.x = pk[0]; s0.y = pk[1]; s0.z = pk[2]; s0.w = pk[3];
        s1.x = pk[4]; s1.y = pk[5]; s1.z = pk[6]; s1.w = pk[7];
        dst[0] = s0; dst[1] = s1;
      }
      if (mf2 < 3) {
#pragma unroll
        for (int rq = 0; rq < 4; ++rq) xw[rq] = xwN[rq];
      }
    }
    score += __shfl_xor(score, 32);
    if (h == 0 && p < E) scoreS[p] = score;

    if (!hasN) break;
    float ss = 0.f;
#pragma unroll
    for (int k8 = 0; k8 < 8; ++k8) {
      ss = fmaf(eaN[k8].x, eaN[k8].x, ss); ss = fmaf(eaN[k8].y, eaN[k8].y, ss);
      ss = fmaf(eaN[k8].z, eaN[k8].z, ss); ss = fmaf(eaN[k8].w, eaN[k8].w, ss);
    }
    ss += __shfl_xor(ss, 32);
    rinC = 1.0f / (sqrtf(ss) + 1e-8f);
#pragma unroll
    for (int ks = 0; ks < 4; ++ks) {
      ebC[ks][0] = cvtpk(eaN[2*ks].x,   eaN[2*ks].y);
      ebC[ks][1] = cvtpk(eaN[2*ks].z,   eaN[2*ks].w);
      ebC[ks][2] = cvtpk(eaN[2*ks+1].x, eaN[2*ks+1].y);
      ebC[ks][3] = cvtpk(eaN[2*ks+1].z, eaN[2*ks+1].w);
    }
    srcC = srcN; p = pn; pn = pnn; hasN = hasNN; eN = eNN;
  }
}

// ---------------- gather: softmax + weighted sum; wide-row fast path ----------------
template<int FUSEW>
__global__ __launch_bounds__(256)
void k_gather(const unsigned* __restrict__ msgp, const float* __restrict__ scoreS,
              const int* __restrict__ rowptr, const int* __restrict__ eidx,
              float* __restrict__ lse, float* __restrict__ wreg,
              float* __restrict__ out, int N)
{
  const int lane = threadIdx.x & 63;
  const int node = blockIdx.x * 4 + (threadIdx.x >> 6);
  if (node >= N) return;
  const int end   = rowptr[node];
  const int start = node ? rowptr[node - 1] : 0;
  const int L     = end - start;

  if (L <= 64) {
    // ---- fast path: 4 rows per load instruction (lane reads 16B of one row) ----
    float sc = (lane < L) ? scoreS[start + lane] : -3.4e38f;
    float mn = sc;
#pragma unroll
    for (int off = 32; off; off >>= 1) mn = fmaxf(mn, __shfl_xor(mn, off));
    float ex = (lane < L) ? __expf(sc - mn) : 0.f;
    float s = ex;
#pragma unroll
    for (int off = 32; off; off >>= 1) s += __shfl_xor(s, off);
    const float w = ex / (s + 1e-16f);           // w==0 for lane>=L
    if (FUSEW) {
      if (lane < L) wreg[eidx[start + lane]] = w;
    } else if (lane == 0) {
      lse[node] = mn + logf(s + 1e-16f);
    }

    const int g = lane & 15;     // uint-quad within row: uints 4g..4g+3
    const int q = lane >> 4;     // which of 4 rows this lane covers
    float acc8[8];
#pragma unroll
    for (int i = 0; i < 8; ++i) acc8[i] = 0.f;
    const int nit = (L + 3) >> 2;
#pragma unroll 2
    for (int it = 0; it < nit; ++it) {
      const int r = 4 * it + q;                          // row (may overrun; w=0)
      const float wj = __shfl(w, r);
      ux4 md = *(const ux4*)(msgp + (long long)(start + r) * 64 + 4 * g);
#pragma unroll
      for (int k = 0; k < 4; ++k) {
        const unsigned u = ((const unsigned*)&md)[k];
        acc8[2*k]   = fmaf(wj, __uint_as_float(u << 16),          acc8[2*k]);
        acc8[2*k+1] = fmaf(wj, __uint_as_float(u & 0xffff0000u), acc8[2*k+1]);
      }
    }
    // reduce across the 4 row-groups (q)
#pragma unroll
    for (int i = 0; i < 8; ++i) {
      acc8[i] += __shfl_xor(acc8[i], 16);
      acc8[i] += __shfl_xor(acc8[i], 32);
    }
    if (lane < 16) {
#pragma unroll
      for (int k = 0; k < 4; ++k) {
        const int u = 4 * lane + k;
        const int ch0 = 32*(u >> 4) + 8*((u >> 1) & 3) + 4*((u >> 3) & 1) + 2*(u & 1);
        float2 o; o.x = acc8[2*k]; o.y = acc8[2*k+1];
        *(float2*)(out + (long long)node * 128 + ch0) = o;
      }
    }
    return;
  }

  // ---- general path (L > 64, rare) ----
  float2 acc; acc.x = 0.f; acc.y = 0.f;
  float m = -3.4e38f, s = 0.f;
  for (int c0 = 0; c0 < L; c0 += 64) {
    const int j = c0 + lane;
    float sc = (j < L) ? scoreS[start + j] : -3.4e38f;
    float cm = sc;
#pragma unroll
    for (int off = 32; off; off >>= 1) cm = fmaxf(cm, __shfl_xor(cm, off));
    const float mn = fmaxf(m, cm);
    float ex = (j < L) ? __expf(sc - mn) : 0.f;
#pragma unroll
    for (int off = 32; off; off >>= 1) ex += __shfl_xor(ex, off);
    s = s * __expf(m - mn) + ex;
    m = mn;
  }
  const float lsev = m + logf(s + 1e-16f);
  if (!FUSEW && lane == 0) lse[node] = lsev;

  for (int c0 = 0; c0 < L; c0 += 64) {
    const int j = c0 + lane;
    float w = (j < L) ? __expf(scoreS[start + j] - lsev) : 0.f;
    if (FUSEW && j < L) wreg[eidx[start + j]] = w;
    const int jn = min(64, L - c0);
#pragma unroll 4
    for (int j2 = 0; j2 < jn; ++j2) {
      float wj = __shfl(w, j2);
      unsigned md = msgp[(long long)(start + c0 + j2) * 64 + lane];
      acc.x = fmaf(wj, __uint_as_float(md << 16),          acc.x);
      acc.y = fmaf(wj, __uint_as_float(md & 0xffff0000u), acc.y);
    }
  }
  const int mf2 = lane >> 4, hh = (lane >> 3) & 1, rq = (lane >> 1) & 3, half = lane & 1;
  const int ch0 = 32*mf2 + 8*rq + 4*hh + 2*half;
  *(float2*)(out + (long long)node * 128 + ch0) = acc;
}

// ---------------- fallback: final weights via pose + lse ----------------
__global__ void k_wfin(int* __restrict__ pw, const int* __restrict__ ei,
                       const float* __restrict__ scoreS, const float* __restrict__ lse,
                       int E){
  for (long long i = (long long)blockIdx.x * 256 + threadIdx.x; i < E;
       i += (long long)gridDim.x * 256) {
    int pos = pw[i];
    float w = __expf(scoreS[pos] - lse[ei[E + i]]);
    pw[i] = __float_as_int(w);
  }
}

extern "C" void kernel_launch(void* const* d_in, const int* in_sizes, int n_in,
                              void* d_out, int out_size, void* d_ws, size_t ws_size,
                              hipStream_t stream)
{
  const float* x    = (const float*)d_in[0];
  const int*   ei   = (const int*)d_in[1];
  const float* ea   = (const float*)d_in[2];
  const float* W1   = (const float*)d_in[3];
  const float* b1   = (const float*)d_in[4];
  const float* W2   = (const float*)d_in[5];
  const float* b2   = (const float*)d_in[6];
  const float* attn = (const float*)d_in[7];
  const int N = in_sizes[0] / 128;
  const int E = in_sizes[2] / 64;
  if (E <= 0 || N <= 0) return;

  float* out   = (float*)d_out;
  float* wregN = out + (long long)N * 128;
  ux4*     Wf     = (ux4*)d_out;
  size_t   offE   = 65536;
  int*     eidxDO = (int*)((char*)d_out + offE);
  size_t   offX   = (offE + (size_t)E * 4 + 255) & ~(size_t)255;
  unsigned* xb    = (unsigned*)((char*)d_out + offX);

  char* wsb = (char*)d_ws;
  unsigned* msgp   = (unsigned*)wsb;
  float*    scoreS = (float*)(wsb + (size_t)E * 256);
  int*      rowptr = (int*)(wsb + (size_t)E * 260);
  float*    lse    = (float*)(wsb + (size_t)E * 260 + (size_t)N * 4);
  int*      eidxWS = (int*)(wsb + (size_t)E * 260 + (size_t)N * 8);
  const size_t need1 = (size_t)E * 260 + (size_t)N * 8;
  const size_t need2 = need1 + (size_t)E * 4;
  if (ws_size < need1) return;
  if ((size_t)out_size < (size_t)N * 128 + (size_t)E) return;
  if ((size_t)N * 512 < offX + (size_t)N * 256) return;

  const bool fused = (ws_size >= need2);
  int* eidx = fused ? eidxWS : eidxDO;

  (void)hipMemsetAsync(rowptr, 0, (size_t)N * 4, stream);
  k_setup<<<1024, 256, 0, stream>>>(x, (uint2*)xb, N * 32, ei, rowptr, E, W1, W2, Wf);
  k_scan<<<1, 1024, 0, stream>>>(rowptr, N);
  k_fill<<<1024, 256, 0, stream>>>(ei, rowptr, fused ? nullptr : (int*)wregN, eidx, E);
  const long long nwaves = ((long long)E + 31) / 32;
  const int grid = (int)min((long long)512, (nwaves + (K1B/64) - 1) / (K1B/64));
  k1_fused<<<grid, K1B, 0, stream>>>(xb, ei, ea, Wf, b1, b2, attn,
                                     eidx, msgp, scoreS, E);
  if (fused) {
    k_gather<1><<<(N + 3) / 4, 256, 0, stream>>>(msgp, scoreS, rowptr, eidx,
                                                 lse, wregN, out, N);
  } else {
    k_gather<0><<<(N + 3) / 4, 256, 0, stream>>>(msgp, scoreS, rowptr, eidx,
                                                 lse, wregN, out, N);
    k_wfin<<<1024, 256, 0, stream>>>((int*)wregN, ei, scoreS, lse, E);
  }
}